// Round 6
// baseline (512.286 us; speedup 1.0000x reference)
//
#include <hip/hip_runtime.h>

// Problem constants (fixed by reference: B=4, C=512, H=W=64, MID=64)
#define BB 4
#define CD 512
#define NP 4096
#define MID 64
#define PSTR 144  // pbuf row stride (halves). NOTE (R5 finding): SQ_LDS_BANK_CONFLICT
                  // books ~6 cyc per ds_read_b128 regardless of stride (structural
                  // width cost, m134); stride tuning is NOT a lever here.

typedef _Float16 half8 __attribute__((ext_vector_type(8)));
typedef _Float16 half4 __attribute__((ext_vector_type(4)));
typedef float floatx4 __attribute__((ext_vector_type(4)));

#define LOG2E 1.4426950408889634f

// ---------------------------------------------------------------------------
// Kernel 1: pack wq|wk|wv -> fp16 [640][512], concat biases (fp32 [640]).
// log2(e) folded into wq/bq so softmax uses raw v_exp_f32 (exp2).
// ---------------------------------------------------------------------------
__global__ __launch_bounds__(256) void prep_w(
    const float* __restrict__ wq, const float* __restrict__ wk,
    const float* __restrict__ wv, const float* __restrict__ bq,
    const float* __restrict__ bk, const float* __restrict__ bv,
    _Float16* __restrict__ w_h, float* __restrict__ bias) {
  int idx = blockIdx.x * 256 + threadIdx.x;
  for (int i = idx; i < 640 * 512; i += gridDim.x * 256) {
    int r = i >> 9, c = i & 511;
    float v = (r < 64) ? wq[(r << 9) + c] * LOG2E
            : (r < 128) ? wk[((r - 64) << 9) + c]
                        : wv[((r - 128) << 9) + c];
    w_h[i] = (_Float16)v;
  }
  if (idx < 640) {
    float v = (idx < 64) ? bq[idx] * LOG2E
            : (idx < 128) ? bk[idx - 64]
                          : bv[idx - 128];
    bias[idx] = v;
  }
}

// ---------------------------------------------------------------------------
// Kernel 2: transpose x [b][c][n] fp32 -> xt [b][n][c] fp16 (64x64 LDS tiles)
// ---------------------------------------------------------------------------
__global__ __launch_bounds__(256) void transpose_x(const float* __restrict__ x,
                                                   _Float16* __restrict__ xt) {
  __shared__ float tile[64][65];
  int b = blockIdx.z, c0 = blockIdx.y * 64, n0 = blockIdx.x * 64;
  int t = threadIdx.x;
  const float* xb = x + (size_t)b * CD * NP;
#pragma unroll
  for (int k = 0; k < 16; k++) {
    int cl = k * 4 + (t >> 6);
    int nl = t & 63;
    tile[cl][nl] = xb[(size_t)(c0 + cl) * NP + n0 + nl];
  }
  __syncthreads();
  _Float16* xtb = xt + ((size_t)b * NP + n0) * CD + c0;
#pragma unroll
  for (int k = 0; k < 2; k++) {
    int nl = k * 32 + (t >> 3);
    int cl = (t & 7) * 8;
    half8 pk;
#pragma unroll
    for (int i = 0; i < 8; i++) pk[i] = (_Float16)tile[cl + i][nl];
    *(half8*)(xtb + (size_t)nl * CD + cl) = pk;
  }
}

// ---------------------------------------------------------------------------
// Kernel 3: fused QKV projection, v3 (occupancy-oriented).
// Grid (10, 32, B) = 1280 blocks (~5/CU). Block = 64 W-rows x 128 n;
// wave w covers its 32-n subtile, all 64 rows. acc[4][2]=32 VGPR, no
// xt-LDS staging (frags straight from L2). V rows bounce through LDS
// for coalesced b128 stores.
// ---------------------------------------------------------------------------
__global__ __launch_bounds__(256) void proj_qkv(
    const _Float16* __restrict__ w_h, const float* __restrict__ bias,
    const _Float16* __restrict__ xt, _Float16* __restrict__ q_h,
    _Float16* __restrict__ k_h, _Float16* __restrict__ v_h) {
  __shared__ _Float16 st[64 * 136];   // 17 KB V-bounce
  int t = threadIdx.x, w = t >> 6, lane = t & 63;
  int col = lane & 15, quad = lane >> 4;
  int rbt = blockIdx.x, nb = blockIdx.y, b = blockIdx.z;
  int r0 = rbt * 64, n0 = nb * 128;
  const _Float16* xtb = xt + ((size_t)b * NP + n0 + w * 32) * CD;

  floatx4 acc[4][2] = {};
  for (int c = 0; c < CD; c += 32) {
    half8 a[4], bf[2];
#pragma unroll
    for (int i = 0; i < 4; i++)
      a[i] = *(const half8*)(w_h + (size_t)(r0 + i * 16 + col) * CD + c + quad * 8);
#pragma unroll
    for (int j = 0; j < 2; j++)
      bf[j] = *(const half8*)(xtb + (size_t)(j * 16 + col) * CD + c + quad * 8);
#pragma unroll
    for (int i = 0; i < 4; i++)
#pragma unroll
      for (int j = 0; j < 2; j++)
        acc[i][j] = __builtin_amdgcn_mfma_f32_16x16x32_f16(a[i], bf[j], acc[i][j], 0, 0, 0);
  }

  if (rbt < 2) {
    // q (rbt=0) or k (rbt=1): store [n][64] packed half4
    _Float16* dst = (rbt == 0 ? q_h : k_h) + (size_t)b * NP * MID;
#pragma unroll
    for (int i = 0; i < 4; i++) {
      float bi[4];
#pragma unroll
      for (int rr = 0; rr < 4; rr++) bi[rr] = bias[r0 + i * 16 + quad * 4 + rr];
#pragma unroll
      for (int j = 0; j < 2; j++) {
        int n = n0 + w * 32 + j * 16 + col;
        half4 pk;
#pragma unroll
        for (int rr = 0; rr < 4; rr++) pk[rr] = (_Float16)(acc[i][j][rr] + bi[rr]);
        *(half4*)(dst + (size_t)n * MID + i * 16 + quad * 4) = pk;
      }
    }
  } else {
    // V rows: bounce via LDS, then 64x128 tile stored as b128 rows
#pragma unroll
    for (int i = 0; i < 4; i++) {
      float bi[4];
#pragma unroll
      for (int rr = 0; rr < 4; rr++) bi[rr] = bias[r0 + i * 16 + quad * 4 + rr];
#pragma unroll
      for (int j = 0; j < 2; j++)
#pragma unroll
        for (int rr = 0; rr < 4; rr++)
          st[(i * 16 + quad * 4 + rr) * 136 + w * 32 + j * 16 + col] =
              (_Float16)(acc[i][j][rr] + bi[rr]);
    }
    __syncthreads();
    int dbase = r0 - 128;
#pragma unroll
    for (int it = 0; it < 4; it++) {
      int u = t + it * 256;
      int row = u >> 4, un = u & 15;
      *(half8*)(v_h + ((size_t)b * CD + dbase + row) * NP + n0 + un * 8) =
          *(const half8*)(st + row * 136 + un * 8);
    }
  }
}

// ---------------------------------------------------------------------------
// Kernel 4: row max of S (log2-domain), v3. Block = 16 q; 4 waves split the
// 4096 keys 4-way. Grid (256, B) = 1024 blocks (4/CU).
// ---------------------------------------------------------------------------
__global__ __launch_bounds__(256) void rowmax(const _Float16* __restrict__ q_h,
                                              const _Float16* __restrict__ k_h,
                                              float* __restrict__ M) {
  int qb = blockIdx.x, b = blockIdx.y;
  int t = threadIdx.x, w = t >> 6, lane = t & 63;
  int col = lane & 15, quad = lane >> 4;
  int q0 = qb * 16;
  const _Float16* qp = q_h + ((size_t)b * NP + q0) * MID;
  half8 bq0 = *(const half8*)(qp + (size_t)col * MID + quad * 8);
  half8 bq1 = *(const half8*)(qp + (size_t)col * MID + 32 + quad * 8);
  const _Float16* kp = k_h + ((size_t)b * NP + (size_t)w * 1024) * MID;
  float m = -1e30f;
#pragma unroll 4
  for (int n = 0; n < 1024; n += 16) {
    half8 ak0 = *(const half8*)(kp + (size_t)(n + col) * MID + quad * 8);
    half8 ak1 = *(const half8*)(kp + (size_t)(n + col) * MID + 32 + quad * 8);
    floatx4 s = {};
    s = __builtin_amdgcn_mfma_f32_16x16x32_f16(ak0, bq0, s, 0, 0, 0);
    s = __builtin_amdgcn_mfma_f32_16x16x32_f16(ak1, bq1, s, 0, 0, 0);
    m = fmaxf(m, fmaxf(fmaxf(s[0], s[1]), fmaxf(s[2], s[3])));
  }
  m = fmaxf(m, __shfl_xor(m, 16));
  m = fmaxf(m, __shfl_xor(m, 32));
  __shared__ float red[4][16];
  if (quad == 0) red[w][col] = m;
  __syncthreads();
  if (t < 16) {
    float mm = fmaxf(fmaxf(red[0][t], red[1][t]), fmaxf(red[2][t], red[3][t]));
    M[(size_t)b * NP + q0 + t] = mm;
  }
}

// ---------------------------------------------------------------------------
// Kernel 5: attention + PV + epilogue, v6 (occupancy 4 blocks/CU).
// Grid 1024 = b(4) x ds(2: 256 d) x qb(128: 32 q); block = 4 waves.
// 128-key chunks: wave w scores ITS 32 keys vs the 32 q -> dbuf pbuf;
// ONE barrier; PV for its private 64d x 32q over the full chunk.
// acc[4][2]=32 VGPR; V frags loaded per-f inside PV (16 waves/CU hide L2
// latency via TLP). launch_bounds(256,4) pins VGPR<=128.
// ---------------------------------------------------------------------------
__global__ __launch_bounds__(256, 4) void attn_pv(
    const _Float16* __restrict__ q_h, const _Float16* __restrict__ k_h,
    const _Float16* __restrict__ v_h, const float* __restrict__ M,
    const float* __restrict__ x, const float* __restrict__ alpha_p,
    float* __restrict__ out) {
  int bid = blockIdx.x;
  int combo = bid & 7;               // (b, ds) -> XCD via round-robin dispatch
  int b = combo >> 1, ds = combo & 1;
  int qb = bid >> 3;                 // 0..127
  int q0 = qb * 32, d0 = ds * 256;

  int t = threadIdx.x, w = t >> 6, lane = t & 63;
  int col = lane & 15, quad = lane >> 4;

  __shared__ _Float16 pbuf[2][32 * PSTR];   // 18.4 KB double-buffered P
  __shared__ float lred[4][2][16];
  __shared__ float lfin[32];

  const _Float16* qp = q_h + ((size_t)b * NP + q0) * MID;
  half8 bq[2][2];
#pragma unroll
  for (int qt = 0; qt < 2; qt++)
#pragma unroll
    for (int h = 0; h < 2; h++)
      bq[qt][h] = *(const half8*)(qp + (size_t)(qt * 16 + col) * MID + h * 32 + quad * 8);
  float Mq[2];
#pragma unroll
  for (int qt = 0; qt < 2; qt++) Mq[qt] = M[(size_t)b * NP + q0 + qt * 16 + col];

  const _Float16* kp = k_h + (size_t)b * NP * MID;
  const _Float16* vp = v_h + ((size_t)(b * CD + d0) + w * 64) * NP;

  floatx4 acc[4][2] = {};            // [dt][qt] = 32 VGPRs, static indices
  float lp[2] = {0.f, 0.f};

  for (int ci = 0; ci < 32; ci++) {
    int nc = ci * 128;
    _Float16* pb = pbuf[ci & 1];

    // ---- score phase: this wave's 32 keys vs the block's 32 q ----
#pragma unroll
    for (int kt = 0; kt < 2; kt++) {
      const _Float16* kr = kp + (size_t)(nc + w * 32 + kt * 16 + col) * MID;
      half8 ak0 = *(const half8*)(kr + quad * 8);
      half8 ak1 = *(const half8*)(kr + 32 + quad * 8);
#pragma unroll
      for (int qt = 0; qt < 2; qt++) {
        floatx4 s = {};
        s = __builtin_amdgcn_mfma_f32_16x16x32_f16(ak0, bq[qt][0], s, 0, 0, 0);
        s = __builtin_amdgcn_mfma_f32_16x16x32_f16(ak1, bq[qt][1], s, 0, 0, 0);
        half4 pk;
#pragma unroll
        for (int r = 0; r < 4; r++) {
          float p = exp2f(s[r] - Mq[qt]);
          lp[qt] += p;
          pk[r] = (_Float16)p;
        }
        *(half4*)(pb + (qt * 16 + col) * PSTR + w * 32 + kt * 16 + quad * 4) = pk;
      }
    }
    __syncthreads();

    // ---- PV phase: private 64d x 32q over the full 128-key chunk ----
#pragma unroll
    for (int f = 0; f < 4; f++) {
      half8 av[4];
#pragma unroll
      for (int dt = 0; dt < 4; dt++)
        av[dt] = *(const half8*)(vp + (size_t)(dt * 16 + col) * NP + nc + f * 32 + quad * 8);
      half8 bp[2];
#pragma unroll
      for (int qt = 0; qt < 2; qt++)
        bp[qt] = *(const half8*)(pb + (qt * 16 + col) * PSTR + f * 32 + quad * 8);
#pragma unroll
      for (int dt = 0; dt < 4; dt++)
#pragma unroll
        for (int qt = 0; qt < 2; qt++)
          acc[dt][qt] = __builtin_amdgcn_mfma_f32_16x16x32_f16(av[dt], bp[qt], acc[dt][qt], 0, 0, 0);
    }
  }

  // l: reduce across quads (keys) within wave, then across waves via LDS
#pragma unroll
  for (int qt = 0; qt < 2; qt++) {
    lp[qt] += __shfl_xor(lp[qt], 16);
    lp[qt] += __shfl_xor(lp[qt], 32);
    if (quad == 0) lred[w][qt][col] = lp[qt];
  }
  __syncthreads();
  if (t < 32) {
    int qt = t >> 4, c = t & 15;
    float l = lred[0][qt][c] + lred[1][qt][c] + lred[2][qt][c] + lred[3][qt][c];
    lfin[t] = alpha_p[0] / l;
  }
  __syncthreads();

  // epilogue: fused alpha/l scale + residual
  const float* xp = x + ((size_t)(b * CD + d0) + w * 64) * NP;
  float* op = out + ((size_t)(b * CD + d0) + w * 64) * NP;
#pragma unroll
  for (int dt = 0; dt < 4; dt++)
#pragma unroll
    for (int qt = 0; qt < 2; qt++) {
      float linv = lfin[qt * 16 + col];
#pragma unroll
      for (int r = 0; r < 4; r++) {
        size_t o = (size_t)(dt * 16 + quad * 4 + r) * NP + q0 + qt * 16 + col;
        op[o] = acc[dt][qt][r] * linv + xp[o];
      }
    }
}

// ---------------------------------------------------------------------------
extern "C" void kernel_launch(void* const* d_in, const int* in_sizes, int n_in,
                              void* d_out, int out_size, void* d_ws, size_t ws_size,
                              hipStream_t stream) {
  const float* x     = (const float*)d_in[0];
  const float* wq    = (const float*)d_in[1];
  const float* bq    = (const float*)d_in[2];
  const float* wk    = (const float*)d_in[3];
  const float* bk    = (const float*)d_in[4];
  const float* wv    = (const float*)d_in[5];
  const float* bv    = (const float*)d_in[6];
  const float* alpha = (const float*)d_in[7];
  float* out = (float*)d_out;

  char* ws = (char*)d_ws;
  _Float16* w_h  = (_Float16*)(ws);                    // 640*512*2   = 655360
  float*    bias = (float*)(ws + 655360);              // 640*4       = 2560
  float*    Mbuf = (float*)(ws + 657920);              // 4*4096*4    = 65536
  _Float16* xt   = (_Float16*)(ws + 723456);           // 4*4096*512*2= 16777216
  _Float16* q_h  = (_Float16*)(ws + 17500672);         // 4*4096*64*2 = 2097152
  _Float16* k_h  = (_Float16*)(ws + 19597824);         // 4*4096*64*2 = 2097152
  _Float16* v_h  = (_Float16*)(ws + 21694976);         // 4*512*4096*2= 16777216

  prep_w<<<1280, 256, 0, stream>>>(wq, wk, wv, bq, bk, bv, w_h, bias);
  transpose_x<<<dim3(64, 8, BB), 256, 0, stream>>>(x, xt);
  proj_qkv<<<dim3(10, 32, BB), 256, 0, stream>>>(w_h, bias, xt, q_h, k_h, v_h);
  rowmax<<<dim3(256, BB), 256, 0, stream>>>(q_h, k_h, Mbuf);
  attn_pv<<<1024, 256, 0, stream>>>(q_h, k_h, v_h, Mbuf, x, alpha, out);
}

// Round 7
// 359.004 us; speedup vs baseline: 1.4270x; 1.4270x over previous
//
#include <hip/hip_runtime.h>

// Problem constants (fixed by reference: B=4, C=512, H=W=64, MID=64)
#define BB 4
#define CD 512
#define NP 4096
#define MID 64
#define CK 64           // attn key-chunk
#define VSTR 72         // V/P LDS row stride (halves): 36 dwords = 4 mod 32 -> spread banks

typedef _Float16 half8 __attribute__((ext_vector_type(8)));
typedef _Float16 half4 __attribute__((ext_vector_type(4)));
typedef float floatx4 __attribute__((ext_vector_type(4)));

#define LOG2E 1.4426950408889634f

// ---------------------------------------------------------------------------
// Kernel 1: pack wq|wk|wv -> fp16 [640][512], biases fp32 [640], log2e folded.
// ---------------------------------------------------------------------------
__global__ __launch_bounds__(256) void prep_w(
    const float* __restrict__ wq, const float* __restrict__ wk,
    const float* __restrict__ wv, const float* __restrict__ bq,
    const float* __restrict__ bk, const float* __restrict__ bv,
    _Float16* __restrict__ w_h, float* __restrict__ bias) {
  int idx = blockIdx.x * 256 + threadIdx.x;
  for (int i = idx; i < 640 * 512; i += gridDim.x * 256) {
    int r = i >> 9, c = i & 511;
    float v = (r < 64) ? wq[(r << 9) + c] * LOG2E
            : (r < 128) ? wk[((r - 64) << 9) + c]
                        : wv[((r - 128) << 9) + c];
    w_h[i] = (_Float16)v;
  }
  if (idx < 640) {
    float v = (idx < 64) ? bq[idx] * LOG2E
            : (idx < 128) ? bk[idx - 64]
                          : bv[idx - 128];
    bias[idx] = v;
  }
}

// ---------------------------------------------------------------------------
// Kernel 2: transpose x [b][c][n] fp32 -> xt [b][n][c] fp16
// ---------------------------------------------------------------------------
__global__ __launch_bounds__(256) void transpose_x(const float* __restrict__ x,
                                                   _Float16* __restrict__ xt) {
  __shared__ float tile[64][65];
  int b = blockIdx.z, c0 = blockIdx.y * 64, n0 = blockIdx.x * 64;
  int t = threadIdx.x;
  const float* xb = x + (size_t)b * CD * NP;
#pragma unroll
  for (int k = 0; k < 16; k++) {
    int cl = k * 4 + (t >> 6);
    int nl = t & 63;
    tile[cl][nl] = xb[(size_t)(c0 + cl) * NP + n0 + nl];
  }
  __syncthreads();
  _Float16* xtb = xt + ((size_t)b * NP + n0) * CD + c0;
#pragma unroll
  for (int k = 0; k < 2; k++) {
    int nl = k * 32 + (t >> 3);
    int cl = (t & 7) * 8;
    half8 pk;
#pragma unroll
    for (int i = 0; i < 8; i++) pk[i] = (_Float16)tile[cl + i][nl];
    *(half8*)(xtb + (size_t)nl * CD + cl) = pk;
  }
}

// ---------------------------------------------------------------------------
// Kernel 3: fused QKV projection (R6 structure; V now stored in chunk-blocked
// layout vc[b][nchunk(64)][dsg(4)][128d][64n] -> 16KB-contiguous attn tiles).
// Grid (10, 32, B): 64 W-rows x 128 n per block.
// ---------------------------------------------------------------------------
__global__ __launch_bounds__(256) void proj_qkv(
    const _Float16* __restrict__ w_h, const float* __restrict__ bias,
    const _Float16* __restrict__ xt, _Float16* __restrict__ q_h,
    _Float16* __restrict__ k_h, _Float16* __restrict__ vc) {
  __shared__ _Float16 st[64 * 136];
  int t = threadIdx.x, w = t >> 6, lane = t & 63;
  int col = lane & 15, quad = lane >> 4;
  int rbt = blockIdx.x, nb = blockIdx.y, b = blockIdx.z;
  int r0 = rbt * 64, n0 = nb * 128;
  const _Float16* xtb = xt + ((size_t)b * NP + n0 + w * 32) * CD;

  floatx4 acc[4][2] = {};
  for (int c = 0; c < CD; c += 32) {
    half8 a[4], bf[2];
#pragma unroll
    for (int i = 0; i < 4; i++)
      a[i] = *(const half8*)(w_h + (size_t)(r0 + i * 16 + col) * CD + c + quad * 8);
#pragma unroll
    for (int j = 0; j < 2; j++)
      bf[j] = *(const half8*)(xtb + (size_t)(j * 16 + col) * CD + c + quad * 8);
#pragma unroll
    for (int i = 0; i < 4; i++)
#pragma unroll
      for (int j = 0; j < 2; j++)
        acc[i][j] = __builtin_amdgcn_mfma_f32_16x16x32_f16(a[i], bf[j], acc[i][j], 0, 0, 0);
  }

  if (rbt < 2) {
    _Float16* dst = (rbt == 0 ? q_h : k_h) + (size_t)b * NP * MID;
#pragma unroll
    for (int i = 0; i < 4; i++) {
      float bi[4];
#pragma unroll
      for (int rr = 0; rr < 4; rr++) bi[rr] = bias[r0 + i * 16 + quad * 4 + rr];
#pragma unroll
      for (int j = 0; j < 2; j++) {
        int n = n0 + w * 32 + j * 16 + col;
        half4 pk;
#pragma unroll
        for (int rr = 0; rr < 4; rr++) pk[rr] = (_Float16)(acc[i][j][rr] + bi[rr]);
        *(half4*)(dst + (size_t)n * MID + i * 16 + quad * 4) = pk;
      }
    }
  } else {
    // V rows d = r0-128 .. +63: bounce via LDS, store chunk-blocked
#pragma unroll
    for (int i = 0; i < 4; i++) {
      float bi[4];
#pragma unroll
      for (int rr = 0; rr < 4; rr++) bi[rr] = bias[r0 + i * 16 + quad * 4 + rr];
#pragma unroll
      for (int j = 0; j < 2; j++)
#pragma unroll
        for (int rr = 0; rr < 4; rr++)
          st[(i * 16 + quad * 4 + rr) * 136 + w * 32 + j * 16 + col] =
              (_Float16)(acc[i][j][rr] + bi[rr]);
    }
    __syncthreads();
    int dbase = r0 - 128;
    int dsg = dbase >> 7, dofs = dbase & 127;
#pragma unroll
    for (int it = 0; it < 4; it++) {
      int u = t + it * 256;
      int row = u >> 4, un = u & 15;           // row 0..63, un 0..15 (8-half units)
      int nc = nb * 2 + (un >> 3);             // chunk index
      int nn = (un & 7) * 8;                   // within-chunk n offset
      size_t dst = ((((size_t)b * 64 + nc) * 4 + dsg) * 128 + dofs + row) * 64 + nn;
      *(half8*)(vc + dst) = *(const half8*)(st + row * 136 + un * 8);
    }
  }
}

// ---------------------------------------------------------------------------
// Kernel 3b: repack K into A-frag-major layout:
// kpk[b][kg(256)][h(2)][lane(64)][8]  where element = K[kg*16+(lane&15)]
// [h*32+(lane>>4)*8+e].  Makes every K A-frag a lane-contiguous 1KB load.
// ---------------------------------------------------------------------------
__global__ __launch_bounds__(256) void repack_k(const _Float16* __restrict__ k_h,
                                                _Float16* __restrict__ kpk) {
  int g = blockIdx.x * 256 + threadIdx.x;     // 131072 groups of 8 halves
  int mg = g & 7, key = (g >> 3) & 4095, b = g >> 15;
  half8 v = *(const half8*)(k_h + ((size_t)b * NP + key) * MID + mg * 8);
  int kg = key >> 4, h = mg >> 2, quad = mg & 3;
  int lane = (key & 15) + quad * 16;
  *(half8*)(kpk + (((size_t)b * 512 + kg * 2 + h) * 64 + lane) * 8) = v;
}

// ---------------------------------------------------------------------------
// Kernel 4: row max (log2-domain). Block = 64 q; 4 waves split keys 4-way,
// streaming kpk contiguously. Grid (64, B).
// ---------------------------------------------------------------------------
__global__ __launch_bounds__(256) void rowmax(const _Float16* __restrict__ q_h,
                                              const _Float16* __restrict__ kpk,
                                              float* __restrict__ M) {
  int qb = blockIdx.x, b = blockIdx.y;
  int t = threadIdx.x, w = t >> 6, lane = t & 63;
  int col = lane & 15, quad = lane >> 4;
  int q0 = qb * 64;
  const _Float16* qp = q_h + ((size_t)b * NP + q0) * MID;
  half8 bq[4][2];
#pragma unroll
  for (int qt = 0; qt < 4; qt++)
#pragma unroll
    for (int h = 0; h < 2; h++)
      bq[qt][h] = *(const half8*)(qp + (size_t)(qt * 16 + col) * MID + h * 32 + quad * 8);
  const _Float16* kb = kpk + (size_t)b * 262144;
  float m[4] = {-1e30f, -1e30f, -1e30f, -1e30f};
#pragma unroll 2
  for (int n = 0; n < 1024; n += 16) {
    int kg = (w * 1024 + n) >> 4;
    half8 ak0 = *(const half8*)(kb + ((size_t)(kg * 2 + 0) * 64 + lane) * 8);
    half8 ak1 = *(const half8*)(kb + ((size_t)(kg * 2 + 1) * 64 + lane) * 8);
#pragma unroll
    for (int qt = 0; qt < 4; qt++) {
      floatx4 s = {};
      s = __builtin_amdgcn_mfma_f32_16x16x32_f16(ak0, bq[qt][0], s, 0, 0, 0);
      s = __builtin_amdgcn_mfma_f32_16x16x32_f16(ak1, bq[qt][1], s, 0, 0, 0);
      m[qt] = fmaxf(m[qt], fmaxf(fmaxf(s[0], s[1]), fmaxf(s[2], s[3])));
    }
  }
  __shared__ float red[4][4][16];
#pragma unroll
  for (int qt = 0; qt < 4; qt++) {
    m[qt] = fmaxf(m[qt], __shfl_xor(m[qt], 16));
    m[qt] = fmaxf(m[qt], __shfl_xor(m[qt], 32));
    if (quad == 0) red[w][qt][col] = m[qt];
  }
  __syncthreads();
  if (t < 64) {
    int qt = t >> 4, c = t & 15;
    float mm = fmaxf(fmaxf(red[0][qt][c], red[1][qt][c]),
                     fmaxf(red[2][qt][c], red[3][qt][c]));
    M[(size_t)b * NP + q0 + t] = mm;
  }
}

// ---------------------------------------------------------------------------
// Kernel 5: attention v7 — LDS-staged, contiguous-read, low-traffic.
// Grid 512 = b(4) x ds(4:128d) x qb(32:128q); block = 4 waves.
// Per 64-key chunk: stage next chunk's V(16KB, contiguous from vc) + K(8KB,
// contiguous from kpk) into dbuf LDS; scores (wave: 32-key strip x 64-q half)
// -> shared pb; barrier; PV (wave: 64d x 64q) from LDS V + pb; barrier.
// Roles: scores: key-strip=w&1, q-half=w>>1.  PV: q-half=w&1, d-half=w>>1.
// ---------------------------------------------------------------------------
__global__ __launch_bounds__(256, 2) void attn_pv(
    const _Float16* __restrict__ q_h, const _Float16* __restrict__ kpk,
    const _Float16* __restrict__ vc, const float* __restrict__ M,
    const float* __restrict__ x, const float* __restrict__ alpha_p,
    float* __restrict__ out) {
  int bid = blockIdx.x;
  int xcd = bid & 7, idx = bid >> 3;
  int combo = xcd * 2 + (idx & 1);     // 0..15
  int b = combo >> 2, ds = combo & 3;
  int qb = idx >> 1;                   // 0..31
  int q0 = qb * 128, d0 = ds * 128;

  int t = threadIdx.x, w = t >> 6, lane = t & 63;
  int col = lane & 15, quad = lane >> 4;

  __shared__ _Float16 vt2[2][128 * VSTR];  // 36.9 KB
  __shared__ _Float16 kt2[2][4096];        // 16 KB (frag-major, unpadded)
  __shared__ _Float16 pb[128 * VSTR];      // 18.4 KB
  __shared__ float lred[4][4][16];
  __shared__ float lfin[128];

  // Q frags for this wave's SCORE q-half (w>>1)
  const _Float16* qp = q_h + ((size_t)b * NP + q0 + (w >> 1) * 64) * MID;
  half8 bq[4][2];
#pragma unroll
  for (int qt = 0; qt < 4; qt++)
#pragma unroll
    for (int h = 0; h < 2; h++)
      bq[qt][h] = *(const half8*)(qp + (size_t)(qt * 16 + col) * MID + h * 32 + quad * 8);
  float Mq[4];
#pragma unroll
  for (int qt = 0; qt < 4; qt++)
    Mq[qt] = M[(size_t)b * NP + q0 + (w >> 1) * 64 + qt * 16 + col];

  const _Float16* kb = kpk + (size_t)b * 262144;
  const _Float16* vb = vc + ((size_t)b * 64 * 4 + ds) * 8192;  // + ci*4*8192

  floatx4 acc[4][4] = {};              // [dt][qt] 64 VGPR, static indices
  float lp[4] = {0.f, 0.f, 0.f, 0.f};

  // ---- stage chunk 0 ----
  {
    const _Float16* vsrc = vb;         // ci=0
    const _Float16* ksrc = kb;         // ci=0
#pragma unroll
    for (int r = 0; r < 4; r++) {
      int u = t + r * 256;
      *(half8*)(&vt2[0][(u >> 3) * VSTR + (u & 7) * 8]) = *(const half8*)(vsrc + u * 8);
    }
#pragma unroll
    for (int r = 0; r < 2; r++) {
      int u = t + r * 256;
      *(half8*)(&kt2[0][u * 8]) = *(const half8*)(ksrc + u * 8);
    }
  }

  for (int ci = 0; ci < 64; ci++) {
    int cur = ci & 1;
    __syncthreads();   // (A) staging of chunk ci visible; prior PV reads done

    // ---- stage chunk ci+1 into other buffer (contiguous loads) ----
    if (ci < 63) {
      const _Float16* vsrc = vb + (size_t)(ci + 1) * 4 * 8192;
      const _Float16* ksrc = kb + (size_t)(ci + 1) * 4096;
#pragma unroll
      for (int r = 0; r < 4; r++) {
        int u = t + r * 256;
        *(half8*)(&vt2[cur ^ 1][(u >> 3) * VSTR + (u & 7) * 8]) =
            *(const half8*)(vsrc + u * 8);
      }
#pragma unroll
      for (int r = 0; r < 2; r++) {
        int u = t + r * 256;
        *(half8*)(&kt2[cur ^ 1][u * 8]) = *(const half8*)(ksrc + u * 8);
      }
    }

    // ---- scores: 32-key strip (w&1) x 64-q half (w>>1) ----
#pragma unroll
    for (int kt = 0; kt < 2; kt++) {
      int kgl = (w & 1) * 2 + kt;      // key 16-group within chunk
      half8 ak0 = *(const half8*)(&kt2[cur][((kgl * 2 + 0) * 64 + lane) * 8]);
      half8 ak1 = *(const half8*)(&kt2[cur][((kgl * 2 + 1) * 64 + lane) * 8]);
#pragma unroll
      for (int qt = 0; qt < 4; qt++) {
        floatx4 s = {};
        s = __builtin_amdgcn_mfma_f32_16x16x32_f16(ak0, bq[qt][0], s, 0, 0, 0);
        s = __builtin_amdgcn_mfma_f32_16x16x32_f16(ak1, bq[qt][1], s, 0, 0, 0);
        half4 pk;
#pragma unroll
        for (int r = 0; r < 4; r++) {
          float p = exp2f(s[r] - Mq[qt]);
          lp[qt] += p;
          pk[r] = (_Float16)p;
        }
        *(half4*)(pb + ((w >> 1) * 64 + qt * 16 + col) * VSTR + kgl * 16 + quad * 4) = pk;
      }
    }
    __syncthreads();   // (B) pb visible; staging writes drained

    // ---- PV: d-half (w>>1) x q-half (w&1) over the 64-key chunk ----
#pragma unroll
    for (int f = 0; f < 2; f++) {
      half8 av[4], bp[4];
#pragma unroll
      for (int dt = 0; dt < 4; dt++)
        av[dt] = *(const half8*)(&vt2[cur][((w >> 1) * 64 + dt * 16 + col) * VSTR + f * 32 + quad * 8]);
#pragma unroll
      for (int qt = 0; qt < 4; qt++)
        bp[qt] = *(const half8*)(pb + ((w & 1) * 64 + qt * 16 + col) * VSTR + f * 32 + quad * 8);
#pragma unroll
      for (int dt = 0; dt < 4; dt++)
#pragma unroll
        for (int qt = 0; qt < 4; qt++)
          acc[dt][qt] = __builtin_amdgcn_mfma_f32_16x16x32_f16(av[dt], bp[qt], acc[dt][qt], 0, 0, 0);
    }
  }

  // ---- l reduction: quads within wave, then across the 2 waves per q-half
#pragma unroll
  for (int qt = 0; qt < 4; qt++) {
    lp[qt] += __shfl_xor(lp[qt], 16);
    lp[qt] += __shfl_xor(lp[qt], 32);
    if (quad == 0) lred[w][qt][col] = lp[qt];
  }
  __syncthreads();
  if (t < 128) {
    int half = t >> 6, qt = (t >> 4) & 3, c = t & 15;
    float l = lred[half * 2][qt][c] + lred[half * 2 + 1][qt][c];
    lfin[t] = alpha_p[0] / l;
  }
  __syncthreads();

  // ---- epilogue: fused alpha/l + residual ----
  const float* xp = x + (size_t)b * CD * NP;
  float* op = out + (size_t)b * CD * NP;
#pragma unroll
  for (int dt = 0; dt < 4; dt++)
#pragma unroll
    for (int qt = 0; qt < 4; qt++) {
      float linv = lfin[(w & 1) * 64 + qt * 16 + col];
#pragma unroll
      for (int r = 0; r < 4; r++) {
        size_t o = (size_t)(d0 + (w >> 1) * 64 + dt * 16 + quad * 4 + r) * NP
                 + q0 + (w & 1) * 64 + qt * 16 + col;
        op[o] = acc[dt][qt][r] * linv + xp[o];
      }
    }
}

// ---------------------------------------------------------------------------
extern "C" void kernel_launch(void* const* d_in, const int* in_sizes, int n_in,
                              void* d_out, int out_size, void* d_ws, size_t ws_size,
                              hipStream_t stream) {
  const float* x     = (const float*)d_in[0];
  const float* wq    = (const float*)d_in[1];
  const float* bq    = (const float*)d_in[2];
  const float* wk    = (const float*)d_in[3];
  const float* bk    = (const float*)d_in[4];
  const float* wv    = (const float*)d_in[5];
  const float* bv    = (const float*)d_in[6];
  const float* alpha = (const float*)d_in[7];
  float* out = (float*)d_out;

  char* ws = (char*)d_ws;
  _Float16* w_h  = (_Float16*)(ws);                    // 640*512*2   = 655360
  float*    bias = (float*)(ws + 655360);              // 2560
  float*    Mbuf = (float*)(ws + 657920);              // 65536
  _Float16* xt   = (_Float16*)(ws + 723456);           // 16777216 (dead after proj)
  _Float16* kpk  = (_Float16*)(ws + 723456);           // 2097152  (aliases xt - repack runs after proj)
  _Float16* q_h  = (_Float16*)(ws + 17500672);         // 2097152
  _Float16* k_h  = (_Float16*)(ws + 19597824);         // 2097152
  _Float16* vc   = (_Float16*)(ws + 21694976);         // 16777216 (chunk-blocked V)

  prep_w<<<1280, 256, 0, stream>>>(wq, wk, wv, bq, bk, bv, w_h, bias);
  transpose_x<<<dim3(64, 8, BB), 256, 0, stream>>>(x, xt);
  proj_qkv<<<dim3(10, 32, BB), 256, 0, stream>>>(w_h, bias, xt, q_h, k_h, vc);
  repack_k<<<512, 256, 0, stream>>>(k_h, kpk);   // xt dead from here; kpk aliases it
  rowmax<<<dim3(64, BB), 256, 0, stream>>>(q_h, kpk, Mbuf);
  attn_pv<<<512, 256, 0, stream>>>(q_h, kpk, vc, Mbuf, x, alpha, out);
}